// Round 2
// baseline (1906.016 us; speedup 1.0000x reference)
//
#include <hip/hip_runtime.h>

#define GRP 8
#define SUBD 64
#define NCODE 1024
#define TLEN 4096
#define NBATCH 8
#define NVEC (NBATCH * TLEN)          // 32768
#define QOUT (NBATCH * 512 * TLEN)    // 16777216
#define BN 256                        // vectors per block
#define NCH 16                        // chunks of 64 codes

// ws layout:
// [0]                : double lossAcc[2]
// [16]               : float e2[2*GRP*NCODE]   (cb1 then cb2)  = 65536 B
// [16+65536]         : int idx1[GRP*NVEC]                      = 1 MB
// [16+65536+1048576] : int idx2[GRP*NVEC]                      = 1 MB

__global__ __launch_bounds__(256) void k_e2(const float* __restrict__ cb1,
                                            const float* __restrict__ cb2,
                                            float* __restrict__ e2) {
    int i = blockIdx.x * 256 + threadIdx.x;      // 0 .. 16383
    const float* c = (i < GRP * NCODE) ? (cb1 + (size_t)i * SUBD)
                                       : (cb2 + (size_t)(i - GRP * NCODE) * SUBD);
    float s = 0.f;
#pragma unroll
    for (int d = 0; d < SUBD; ++d) s = __builtin_fmaf(c[d], c[d], s);
    e2[i] = s;
}

// Register-blocked argmin GEMM.
// Block: 256 threads = 4 waves; stages x[256 rows][64 d] into LDS (swizzled).
// Wave w owns rows [w*64, w*64+64); lane = ng*8+kg (ng,kg in 0..7).
// Thread: 8 rows (n0..n0+7) x 8 codes (k = ch*64 + kg + 8j), acc[8][8].
// LDS swizzle: element (row,d) at row*64 + ((d>>2) ^ ((row>>3)&7))*4 + (d&3)
// so the GEMM's 8 ng-distinct b128 reads hit 8 distinct bank-starts.
// Exactness: xe per (n,k) is ONE ascending-d fma chain; dist = fl(x2+e2)-2*acc
// (2*acc exact); per-thread k ascending + lexicographic (dist,idx) reduce
// == reference first-index argmin.
template <int STAGE2>
__global__ __launch_bounds__(256, 2) void k_argmin(
    const float* __restrict__ x,
    const float* __restrict__ cb_res,   // cb1 (residual gather; unused stage1)
    const float* __restrict__ cb,       // codebook to search
    const float* __restrict__ e2,       // e2 row for cb (8*1024)
    const int* __restrict__ idxPrev,    // idx1 (stage2 only)
    int* __restrict__ idxOut,
    float* __restrict__ outIdxF,
    double* __restrict__ lossAcc)
{
    extern __shared__ float xs[];       // [256][64] floats, swizzled = 64 KB
    const int tid = threadIdx.x;
    const int w = tid >> 6, lane = tid & 63;
    const int ng = lane >> 3, kg = lane & 7;
    const int g = blockIdx.y, bz = blockIdx.z;
    const int t0 = blockIdx.x * BN;

    // ---- stage x tile into LDS (coalesced 1 KB rows, swizzled scatter) ----
    {
        const float* xbase = x + ((size_t)(bz * 512 + g * SUBD)) * TLEN + t0;
#pragma unroll
        for (int p = 0; p < 16; ++p) {
            int d = p * 4 + w;
            float4 v = *(const float4*)(xbase + (size_t)d * TLEN + lane * 4);
            int sb = d >> 2, dd = d & 3;
#pragma unroll
            for (int ii = 0; ii < 4; ++ii) {
                int row = lane * 4 + ii;
                int slot = sb ^ ((row >> 3) & 7);
                xs[row * 64 + slot * 4 + dd] = ((const float*)&v)[ii];
            }
        }
    }
    __syncthreads();

    // ---- per-row pass: (stage2: residual update + loss) + x2 fma chain ----
    float myx2;
    double ls = 0.0;
    {
        const int swz = (tid >> 3) & 7;
        float* rowp = xs + tid * 64;
        float xx = 0.f;
        if (STAGE2) {
            int nv = bz * TLEN + t0 + tid;
            int i1 = idxPrev[g * NVEC + nv];
            const float4* zr = (const float4*)(cb_res + ((size_t)g * NCODE + i1) * SUBD);
#pragma unroll
            for (int s = 0; s < 16; ++s) {
                float4* vp = (float4*)(rowp + ((s ^ swz) << 2));
                float4 v = *vp;
                float4 z = zr[s];
#pragma unroll
                for (int dd = 0; dd < 4; ++dd) {
                    float r = ((float*)&v)[dd];
                    float zz = ((const float*)&z)[dd];
                    float tt = zz - r;            // fl(z - r)        (loss term)
                    float zst = r + tt;           // fl(r + tt)
                    ls += (double)(tt * tt);
                    float r2 = r - zst;           // fl(r - zst)  -> residual2
                    ((float*)&v)[dd] = r2;
                    xx = __builtin_fmaf(r2, r2, xx);   // ascending-d chain
                }
                *vp = v;
            }
        } else {
#pragma unroll
            for (int s = 0; s < 16; ++s) {
                float4 v = *(const float4*)(rowp + ((s ^ swz) << 2));
#pragma unroll
                for (int dd = 0; dd < 4; ++dd) {
                    float r = ((const float*)&v)[dd];
                    xx = __builtin_fmaf(r, r, xx);
                }
            }
        }
        myx2 = xx;
    }
    __syncthreads();

    // ---- GEMM + argmin ----
    const float* cbg = cb + (size_t)g * NCODE * SUBD;
    const float* e2g = e2 + g * NCODE;
    const int n0 = w * 64 + ng * 8;

    float x2r[8];
#pragma unroll
    for (int i = 0; i < 8; ++i) x2r[i] = __shfl(myx2, ng * 8 + i, 64);

    float best[8];
    int bidx[8];
#pragma unroll
    for (int i = 0; i < 8; ++i) { best[i] = 1e30f; bidx[i] = 0; }

    for (int ch = 0; ch < NCH; ++ch) {
        float acc[8][8];
#pragma unroll
        for (int i = 0; i < 8; ++i)
#pragma unroll
            for (int j = 0; j < 8; ++j) acc[i][j] = 0.f;

        const int kb = ch * 64 + kg;
        for (int s = 0; s < 16; ++s) {
            float4 cf[8], xf[8];
            const int slot = (s ^ ng) << 2;
#pragma unroll
            for (int j = 0; j < 8; ++j)
                cf[j] = *(const float4*)(cbg + (size_t)(kb + 8 * j) * SUBD + s * 4);
#pragma unroll
            for (int i = 0; i < 8; ++i)
                xf[i] = *(const float4*)(xs + (n0 + i) * 64 + slot);
#pragma unroll
            for (int dd = 0; dd < 4; ++dd)
#pragma unroll
                for (int i = 0; i < 8; ++i)
#pragma unroll
                    for (int j = 0; j < 8; ++j)
                        acc[i][j] = __builtin_fmaf(((const float*)&xf[i])[dd],
                                                   ((const float*)&cf[j])[dd],
                                                   acc[i][j]);
        }
#pragma unroll
        for (int j = 0; j < 8; ++j) {
            int k = kb + 8 * j;
            float e2k = e2g[k];
#pragma unroll
            for (int i = 0; i < 8; ++i) {
                float tv = x2r[i] + e2k;                       // fl(x2 + e2)
                float dist = __builtin_fmaf(-2.0f, acc[i][j], tv);  // fl(tv - 2a)
                if (dist < best[i]) { best[i] = dist; bidx[i] = k; }
            }
        }
    }

    // ---- reduce across the 8 kg lanes (lexicographic: dist, then idx) ----
#pragma unroll
    for (int i = 0; i < 8; ++i) {
        float bd = best[i];
        int bi = bidx[i];
#pragma unroll
        for (int m = 1; m < 8; m <<= 1) {
            float od = __shfl_xor(bd, m, 64);
            int oi = __shfl_xor(bi, m, 64);
            if (od < bd || (od == bd && oi < bi)) { bd = od; bi = oi; }
        }
        if (kg == 0) {
            int nv = bz * TLEN + t0 + n0 + i;
            idxOut[g * NVEC + nv] = bi;
            outIdxF[(size_t)g * NVEC + nv] = (float)bi;
        }
    }

    if (STAGE2) {
#pragma unroll
        for (int off = 32; off; off >>= 1) ls += __shfl_down(ls, off, 64);
        if (lane == 0) atomicAdd(lossAcc, ls);
    }
}

__global__ __launch_bounds__(256) void k_out(const float* __restrict__ x,
                                             const float* __restrict__ cb1,
                                             const float* __restrict__ cb2,
                                             const int* __restrict__ idx1,
                                             const int* __restrict__ idx2,
                                             float* __restrict__ qout,
                                             double* __restrict__ lossAcc) {
    int t = blockIdx.x * 256 + threadIdx.x;
    int g = blockIdx.y, b = blockIdx.z;
    int n = b * TLEN + t;
    int i1 = idx1[g * NVEC + n];
    int i2 = idx2[g * NVEC + n];
    const float4* z1v = (const float4*)(cb1 + ((size_t)g * NCODE + i1) * SUBD);
    const float4* z2v = (const float4*)(cb2 + ((size_t)g * NCODE + i2) * SUBD);
    const float* xp = x + ((size_t)(b * 512 + g * SUBD)) * TLEN + t;
    float* op = qout + ((size_t)(b * 512 + g * SUBD)) * TLEN + t;
    double ls = 0.0;
#pragma unroll
    for (int j = 0; j < SUBD / 4; ++j) {
        float4 a = z1v[j];
        float4 c = z2v[j];
#pragma unroll
        for (int i = 0; i < 4; ++i) {
            int d = 4 * j + i;
            float r = xp[(size_t)d * TLEN];
            float z1 = (&a.x)[i];
            float z2 = (&c.x)[i];
            float t1 = z1 - r;
            float zst1 = r + t1;
            float r2 = r - zst1;
            float t2 = z2 - r2;
            float zst2 = r2 + t2;
            float q = zst1 + zst2;
            op[(size_t)d * TLEN] = q;
            ls += (double)(t2 * t2);
        }
    }
    for (int off = 32; off; off >>= 1) ls += __shfl_down(ls, off, 64);
    __shared__ double wsr[4];
    int lane = threadIdx.x & 63, wv = threadIdx.x >> 6;
    if (lane == 0) wsr[wv] = ls;
    __syncthreads();
    if (threadIdx.x == 0) atomicAdd(lossAcc + 1, wsr[0] + wsr[1] + wsr[2] + wsr[3]);
}

__global__ void k_final(float* __restrict__ lossOut, const double* __restrict__ lossAcc) {
    // loss_i = 1.25 * mean_i ; total = (l1+l2)/2 = 0.625*(m1+m2)
    double m = (lossAcc[0] + lossAcc[1]) / (double)QOUT;
    lossOut[0] = (float)(0.625 * m);
}

extern "C" void kernel_launch(void* const* d_in, const int* in_sizes, int n_in,
                              void* d_out, int out_size, void* d_ws, size_t ws_size,
                              hipStream_t stream) {
    const float* x   = (const float*)d_in[0];
    const float* cb1 = (const float*)d_in[1];
    const float* cb2 = (const float*)d_in[2];
    float* out = (float*)d_out;

    char* ws = (char*)d_ws;
    double* lossAcc = (double*)ws;
    float* e2   = (float*)(ws + 16);
    int*   idx1 = (int*)(ws + 16 + 65536);
    int*   idx2 = (int*)(ws + 16 + 65536 + 1048576);

    hipMemsetAsync(ws, 0, 16, stream);

    k_e2<<<dim3(64), dim3(256), 0, stream>>>(cb1, cb2, e2);

    dim3 grid(TLEN / BN, GRP, NBATCH);          // (16, 8, 8)
    float* outIdx = out + QOUT + 1;
    k_argmin<0><<<grid, dim3(256), 65536, stream>>>(x, cb1, cb1, e2,
                                                    nullptr, idx1, outIdx, nullptr);
    k_argmin<1><<<grid, dim3(256), 65536, stream>>>(x, cb1, cb2, e2 + GRP * NCODE,
                                                    idx1, idx2, outIdx + (size_t)GRP * NVEC,
                                                    lossAcc);
    dim3 gridO(TLEN / 256, GRP, NBATCH);
    k_out<<<gridO, dim3(256), 0, stream>>>(x, cb1, cb2, idx1, idx2, out, lossAcc);
    k_final<<<1, 1, 0, stream>>>(out + QOUT, lossAcc);
}

// Round 3
// 1050.071 us; speedup vs baseline: 1.8151x; 1.8151x over previous
//
#include <hip/hip_runtime.h>

#define GRP 8
#define SUBD 64
#define NCODE 1024
#define TLEN 4096
#define NBATCH 8
#define NVEC (NBATCH * TLEN)          // 32768
#define QOUT (NBATCH * 512 * TLEN)    // 16777216
#define ROWS 128                      // x rows per block
#define NCH 16                        // chunks of 64 codes

// ws layout (bytes):
// [0]        double lossAcc[2]
// [16]       float e2[2*GRP*NCODE]            64 KB
// [65552]    int idx1[GRP*NVEC]               1 MB
// [1114128]  int idx2[GRP*NVEC]               1 MB
// [2162704]  float cbT1[GRP*SUBD*NCODE]       2 MB   [g][d][k]
// [4259856]  float cbT2[GRP*SUBD*NCODE]       2 MB
#define WS_E2   16
#define WS_IDX1 (16 + 65536)
#define WS_IDX2 (WS_IDX1 + 1048576)
#define WS_CBT1 (WS_IDX2 + 1048576)
#define WS_CBT2 (WS_CBT1 + 2097152)

typedef const __attribute__((address_space(1))) char GCHAR;
typedef __attribute__((address_space(3))) char LCHAR;

__global__ __launch_bounds__(256) void k_e2(const float* __restrict__ cb1,
                                            const float* __restrict__ cb2,
                                            float* __restrict__ e2) {
    int i = blockIdx.x * 256 + threadIdx.x;      // 0 .. 16383
    const float* c = (i < GRP * NCODE) ? (cb1 + (size_t)i * SUBD)
                                       : (cb2 + (size_t)(i - GRP * NCODE) * SUBD);
    float s = 0.f;
#pragma unroll
    for (int d = 0; d < SUBD; ++d) s = __builtin_fmaf(c[d], c[d], s);
    e2[i] = s;
}

// cbT[g][d][k] = cb[g][k][d]; per-lane k contiguous -> stores coalesced per d.
__global__ __launch_bounds__(256) void k_tr(const float* __restrict__ cb1,
                                            const float* __restrict__ cb2,
                                            float* __restrict__ cbT1,
                                            float* __restrict__ cbT2) {
    int i = blockIdx.x * 256 + threadIdx.x;      // 0 .. 16383
    int sel = i >> 13, g = (i >> 10) & 7, k = i & 1023;
    const float* src = (sel ? cb2 : cb1) + ((size_t)g * NCODE + k) * SUBD;
    float* dst = (sel ? cbT2 : cbT1) + (size_t)g * SUBD * NCODE + k;
#pragma unroll
    for (int s = 0; s < 16; ++s) {
        float4 v = ((const float4*)src)[s];
#pragma unroll
        for (int dd = 0; dd < 4; ++dd) dst[(size_t)(4 * s + dd) * NCODE] = ((const float*)&v)[dd];
    }
}

// d-major argmin GEMM. Block: 256 thr = 4 waves, 128 rows.
// LDS: xs[64 d][128 rows] (staged via global_load_lds, x is d-major in global),
//      e2s[1024], x2s[128].
// Wave w: rows [w*32, w*32+32). lane: kg=lane>>3 (codes), ng=lane&7 (rows).
// Thread: 4 rows (n0 = w*32+ng*4) x 8 codes (k0 = kb+kg*8), acc[4][8].
// Per d: 1 ds_read_b128 (x, bcast over kg) + 2 global dwordx4 (cbT, bcast over ng)
//        + 32 fma.  Each acc chain is ascending-d fma == reference.
template <int STAGE2>
__global__ __launch_bounds__(256, 4) void k_argmin(
    const float* __restrict__ x,
    const float* __restrict__ cbRes,    // cb1 row-major (stage2 gather)
    const float* __restrict__ cbT,      // transposed codebook to search
    const float* __restrict__ e2,       // e2 row for this codebook (8*1024)
    const int* __restrict__ idxPrev,
    int* __restrict__ idxOut,
    float* __restrict__ outIdxF,
    double* __restrict__ lossAcc)
{
    extern __shared__ float lds[];
    float* xs  = lds;                    // 64*128
    float* e2s = lds + 64 * ROWS;        // 1024
    float* x2s = e2s + NCODE;            // 128

    const int tid = threadIdx.x, w = tid >> 6, lane = tid & 63;
    const int g = blockIdx.y, bz = blockIdx.z;
    const int t0 = blockIdx.x * ROWS;

    // ---- stage x tile: 32 instrs (2 d-rows each), 8 per wave; linear dest ----
    {
        const float* xsrc = x + ((size_t)(bz * 512 + g * SUBD)) * TLEN + t0;
#pragma unroll
        for (int q = 0; q < 8; ++q) {
            int inst = w * 8 + q;                 // 0..31
            int d = inst * 2 + (lane >> 5);
            const float* gp = xsrc + (size_t)d * TLEN + (lane & 31) * 4;
            float* lp = xs + inst * 256;          // wave-uniform base
            __builtin_amdgcn_global_load_lds((GCHAR*)gp, (LCHAR*)lp, 16, 0, 0);
        }
        // e2 slab for this g: 4 KB, 4 instrs (wave w does instr w)
        const float* ep = e2 + g * NCODE + w * 256 + lane * 4;
        float* lp = e2s + w * 256;
        __builtin_amdgcn_global_load_lds((GCHAR*)ep, (LCHAR*)lp, 16, 0, 0);
    }
    __syncthreads();

    // ---- per-row pass (threads 0..127): stage2 residual update + x2 chain ----
    double ls = 0.0;
    if (tid < ROWS) {
        float xx = 0.f;
        if (STAGE2) {
            int nv = bz * TLEN + t0 + tid;
            int i1 = idxPrev[g * NVEC + nv];
            const float4* zr = (const float4*)(cbRes + ((size_t)g * NCODE + i1) * SUBD);
#pragma unroll
            for (int s = 0; s < 16; ++s) {
                float4 z = zr[s];
#pragma unroll
                for (int dd = 0; dd < 4; ++dd) {
                    int d = 4 * s + dd;
                    float r = xs[d * ROWS + tid];
                    float zz = ((const float*)&z)[dd];
                    float tt = zz - r;            // fl(z - r)   (loss term)
                    float zst = r + tt;           // fl(r + tt)
                    ls += (double)(tt * tt);
                    float r2 = r - zst;           // fl(r - zst) -> residual2
                    xs[d * ROWS + tid] = r2;
                    xx = __builtin_fmaf(r2, r2, xx);   // ascending-d chain
                }
            }
        } else {
#pragma unroll
            for (int d = 0; d < SUBD; ++d) {
                float r = xs[d * ROWS + tid];
                xx = __builtin_fmaf(r, r, xx);
            }
        }
        x2s[tid] = xx;
    }
    __syncthreads();

    // ---- GEMM + argmin ----
    const int kg = lane >> 3, ng = lane & 7;
    const int n0 = w * 32 + ng * 4;
    float4 xv2 = *(const float4*)(x2s + n0);
    float x2r[4];
#pragma unroll
    for (int i = 0; i < 4; ++i) x2r[i] = ((const float*)&xv2)[i];

    float best[4];
    int bidx[4];
#pragma unroll
    for (int i = 0; i < 4; ++i) { best[i] = 1e30f; bidx[i] = 0; }

    const float* cbTg = cbT + (size_t)g * SUBD * NCODE;   // [d][1024]

    for (int ch = 0; ch < NCH; ++ch) {
        const int kb = ch * 64;
        const float* cp = cbTg + kb + kg * 8;
        float acc[4][8];
#pragma unroll
        for (int i = 0; i < 4; ++i)
#pragma unroll
            for (int j = 0; j < 8; ++j) acc[i][j] = 0.f;

#pragma unroll 2
        for (int d = 0; d < SUBD; ++d) {
            float4 xa = *(const float4*)(xs + d * ROWS + n0);
            float4 c0 = *(const float4*)(cp + (size_t)d * NCODE);
            float4 c1 = *(const float4*)(cp + (size_t)d * NCODE + 4);
#pragma unroll
            for (int i = 0; i < 4; ++i) {
                float xv = ((const float*)&xa)[i];
#pragma unroll
                for (int j = 0; j < 4; ++j) {
                    acc[i][j]     = __builtin_fmaf(xv, ((const float*)&c0)[j], acc[i][j]);
                    acc[i][j + 4] = __builtin_fmaf(xv, ((const float*)&c1)[j], acc[i][j + 4]);
                }
            }
        }

        float4 eq0 = *(const float4*)(e2s + kb + kg * 8);
        float4 eq1 = *(const float4*)(e2s + kb + kg * 8 + 4);
#pragma unroll
        for (int j = 0; j < 8; ++j) {
            float e2k = (j < 4) ? ((const float*)&eq0)[j] : ((const float*)&eq1)[j - 4];
            int k = kb + kg * 8 + j;
#pragma unroll
            for (int i = 0; i < 4; ++i) {
                float tv = x2r[i] + e2k;                            // fl(x2 + e2)
                float dist = __builtin_fmaf(-2.0f, acc[i][j], tv);  // fl(tv - 2a)
                if (dist < best[i]) { best[i] = dist; bidx[i] = k; }
            }
        }
    }

    // ---- lexicographic reduce across kg (lanes differ in bits 3..5) ----
#pragma unroll
    for (int i = 0; i < 4; ++i) {
        float bd = best[i];
        int bi = bidx[i];
#pragma unroll
        for (int m = 8; m < 64; m <<= 1) {
            float od = __shfl_xor(bd, m, 64);
            int oi = __shfl_xor(bi, m, 64);
            if (od < bd || (od == bd && oi < bi)) { bd = od; bi = oi; }
        }
        if (kg == 0) {
            int nv = bz * TLEN + t0 + n0 + i;
            idxOut[g * NVEC + nv] = bi;
            outIdxF[(size_t)g * NVEC + nv] = (float)bi;
        }
    }

    if (STAGE2) {
#pragma unroll
        for (int off = 32; off; off >>= 1) ls += __shfl_down(ls, off, 64);
        if (lane == 0) atomicAdd(lossAcc, ls);
    }
}

__global__ __launch_bounds__(256) void k_out(const float* __restrict__ x,
                                             const float* __restrict__ cb1,
                                             const float* __restrict__ cb2,
                                             const int* __restrict__ idx1,
                                             const int* __restrict__ idx2,
                                             float* __restrict__ qout,
                                             double* __restrict__ lossAcc) {
    int t = blockIdx.x * 256 + threadIdx.x;
    int g = blockIdx.y, b = blockIdx.z;
    int n = b * TLEN + t;
    int i1 = idx1[g * NVEC + n];
    int i2 = idx2[g * NVEC + n];
    const float4* z1v = (const float4*)(cb1 + ((size_t)g * NCODE + i1) * SUBD);
    const float4* z2v = (const float4*)(cb2 + ((size_t)g * NCODE + i2) * SUBD);
    const float* xp = x + ((size_t)(b * 512 + g * SUBD)) * TLEN + t;
    float* op = qout + ((size_t)(b * 512 + g * SUBD)) * TLEN + t;
    double ls = 0.0;
#pragma unroll
    for (int j = 0; j < SUBD / 4; ++j) {
        float4 a = z1v[j];
        float4 c = z2v[j];
#pragma unroll
        for (int i = 0; i < 4; ++i) {
            int d = 4 * j + i;
            float r = xp[(size_t)d * TLEN];
            float z1 = (&a.x)[i];
            float z2 = (&c.x)[i];
            float t1 = z1 - r;
            float zst1 = r + t1;
            float r2 = r - zst1;
            float t2 = z2 - r2;
            float zst2 = r2 + t2;
            float q = zst1 + zst2;
            op[(size_t)d * TLEN] = q;
            ls += (double)(t2 * t2);
        }
    }
    for (int off = 32; off; off >>= 1) ls += __shfl_down(ls, off, 64);
    __shared__ double wsr[4];
    int lane = threadIdx.x & 63, wv = threadIdx.x >> 6;
    if (lane == 0) wsr[wv] = ls;
    __syncthreads();
    if (threadIdx.x == 0) atomicAdd(lossAcc + 1, wsr[0] + wsr[1] + wsr[2] + wsr[3]);
}

__global__ void k_final(float* __restrict__ lossOut, const double* __restrict__ lossAcc) {
    double m = (lossAcc[0] + lossAcc[1]) / (double)QOUT;
    lossOut[0] = (float)(0.625 * m);
}

extern "C" void kernel_launch(void* const* d_in, const int* in_sizes, int n_in,
                              void* d_out, int out_size, void* d_ws, size_t ws_size,
                              hipStream_t stream) {
    const float* x   = (const float*)d_in[0];
    const float* cb1 = (const float*)d_in[1];
    const float* cb2 = (const float*)d_in[2];
    float* out = (float*)d_out;

    char* ws = (char*)d_ws;
    double* lossAcc = (double*)ws;
    float* e2   = (float*)(ws + WS_E2);
    int*   idx1 = (int*)(ws + WS_IDX1);
    int*   idx2 = (int*)(ws + WS_IDX2);
    float* cbT1 = (float*)(ws + WS_CBT1);
    float* cbT2 = (float*)(ws + WS_CBT2);

    hipMemsetAsync(ws, 0, 16, stream);

    k_e2<<<dim3(64), dim3(256), 0, stream>>>(cb1, cb2, e2);
    k_tr<<<dim3(64), dim3(256), 0, stream>>>(cb1, cb2, cbT1, cbT2);

    const int ldsBytes = (64 * ROWS + NCODE + ROWS) * 4;   // 37376
    dim3 grid(TLEN / ROWS, GRP, NBATCH);                   // (32, 8, 8)
    float* outIdx = out + QOUT + 1;
    k_argmin<0><<<grid, dim3(256), ldsBytes, stream>>>(x, cb1, cbT1, e2,
                                                       nullptr, idx1, outIdx, nullptr);
    k_argmin<1><<<grid, dim3(256), ldsBytes, stream>>>(x, cb1, cbT2, e2 + GRP * NCODE,
                                                       idx1, idx2, outIdx + (size_t)GRP * NVEC,
                                                       lossAcc);
    dim3 gridO(TLEN / 256, GRP, NBATCH);
    k_out<<<gridO, dim3(256), 0, stream>>>(x, cb1, cb2, idx1, idx2, out, lossAcc);
    k_final<<<1, 1, 0, stream>>>(out + QOUT, lossAcc);
}